// Round 9
// baseline (1095.031 us; speedup 1.0000x reference)
//
#include <hip/hip_runtime.h>
#include <stdint.h>

#define EMB 100
#define HW2 25           // uint2 (4 bf16) per row (row-major views)
#define V4_PER_ROW 25
#define BSHIFT 8         // 256 rows per bucket
#define NBMAX 1024
#define TP 256
#define EP 32

#define NSLICE 7         // 7 slices x 16 dims (112, zero-padded from 100)
#define SLW 8            // dwords (2-dim pairs) per row per slice

#define SCAN_T 256
#define SCAN_E 32

// ---------------- bf16 helpers ----------------
static __device__ __forceinline__ uint32_t pack_bf16(float a, float b) {
    uint32_t ua = __float_as_uint(a);
    uint32_t ub = __float_as_uint(b);
    ua = (ua + 0x7FFFu + ((ua >> 16) & 1u)) >> 16;
    ub = (ub + 0x7FFFu + ((ub >> 16) & 1u)) >> 16;
    return ua | (ub << 16);
}
static __device__ __forceinline__ float bflo(uint32_t p) { return __uint_as_float(p << 16); }
static __device__ __forceinline__ float bfhi(uint32_t p) { return __uint_as_float(p & 0xFFFF0000u); }

// fp32 row-major -> slice-major packed bf16 (zero-padded to 112 dims)
__global__ void convert_sl(const float2* __restrict__ x, uint32_t* __restrict__ xs, int nrows) {
    const int slice = blockIdx.y;
    const int tid = blockIdx.x * blockDim.x + threadIdx.x;   // dword within slice
    if (tid >= nrows * SLW) return;
    const int row = tid >> 3, j = tid & 7;
    const int d0 = slice * 16 + j * 2;
    uint32_t v = 0;
    if (d0 < EMB) {
        float2 f = x[(size_t)row * 50 + slice * SLW + j];
        v = pack_bf16(f.x, f.y);
    }
    xs[(size_t)slice * nrows * SLW + tid] = v;
}

// ---------------- batch-user map ----------------
__global__ void map_build(const int* __restrict__ user, uint32_t* __restrict__ map, int batch) {
    int i = blockIdx.x * blockDim.x + threadIdx.x;
    if (i < batch) atomicMin(&map[user[i]], (uint32_t)i);
}

// ---------------- pass 1: per-(block,bucket) counts ----------------
__global__ __launch_bounds__(TP) void pass1_count(
    const int* __restrict__ ra, int na, const int* __restrict__ ru, int nu,
    const uint32_t* __restrict__ map, int* __restrict__ countsT,
    int nblk, int nbA, int nbTot)
{
    __shared__ int lc[NBMAX];
    const int blk = blockIdx.x;
    for (int i = threadIdx.x; i < nbTot; i += TP) lc[i] = 0;
    __syncthreads();
    const int base = blk * (TP * EP);
    const int n = na + nu;
    for (int i = 0; i < EP; ++i) {
        int e = base + i * TP + threadIdx.x;
        int b = -1;
        if (e < na) {
            b = __builtin_nontemporal_load(ra + e) >> BSHIFT;
        } else if (e < n) {
            int r = __builtin_nontemporal_load(ru + (e - na));
            if (map[r] != 0xFFFFFFFFu) b = nbA + (r >> BSHIFT);
        }
        if (b >= 0) atomicAdd(&lc[b], 1);
    }
    __syncthreads();
    for (int i = threadIdx.x; i < nbTot; i += TP)
        countsT[(size_t)i * nblk + blk] = lc[i];
}

// ---------------- 3-phase exclusive scan over countsT ----------------
__global__ void scan_blocks(const int* __restrict__ in, int* __restrict__ out,
                            int* __restrict__ sums, int n) {
    __shared__ int smem[SCAN_T];
    const int b = blockIdx.x, tid = threadIdx.x;
    const int base = b * SCAN_T * SCAN_E + tid * SCAN_E;
    int loc[SCAN_E];
    int s = 0;
    for (int i = 0; i < SCAN_E; ++i) {
        int idx = base + i;
        int v = (idx < n) ? in[idx] : 0;
        loc[i] = s; s += v;
    }
    smem[tid] = s; __syncthreads();
    for (int off = 1; off < SCAN_T; off <<= 1) {
        int v = (tid >= off) ? smem[tid - off] : 0;
        __syncthreads();
        smem[tid] += v;
        __syncthreads();
    }
    int pre = (tid == 0) ? 0 : smem[tid - 1];
    if (tid == SCAN_T - 1) sums[b] = smem[tid];
    for (int i = 0; i < SCAN_E; ++i) {
        int idx = base + i;
        if (idx < n) out[idx] = pre + loc[i];
    }
}

__global__ void scan_mid(int* __restrict__ sums, int nb, int* __restrict__ total_out) {
    __shared__ int sh[256];
    const int t = threadIdx.x;
    int v = (t < nb) ? sums[t] : 0;
    sh[t] = v; __syncthreads();
    for (int off = 1; off < 256; off <<= 1) {
        int u = (t >= off) ? sh[t - off] : 0;
        __syncthreads();
        sh[t] += u;
        __syncthreads();
    }
    if (t < nb) sums[t] = sh[t];
    if (t == 255) *total_out = sh[255];
}

__global__ void scan_fixup(int* __restrict__ out, const int* __restrict__ sums, int n) {
    const int b = blockIdx.x;
    if (b == 0) return;
    const int add = sums[b - 1];
    const int base = b * SCAN_T * SCAN_E + threadIdx.x * SCAN_E;
    for (int i = 0; i < SCAN_E; ++i) {
        int idx = base + i;
        if (idx < n) out[idx] += add;
    }
}

__global__ void extract_bases(const int* __restrict__ scanned, int nblk, int nbTot,
                              const int* __restrict__ total, int* __restrict__ bases,
                              int* __restrict__ rpA_end, int nnzA, int* __restrict__ rpU_end) {
    int t = blockIdx.x * blockDim.x + threadIdx.x;
    if (t < nbTot) bases[t] = scanned[(size_t)t * nblk];
    if (t == 0) {
        int tot = *total;
        bases[nbTot] = tot;
        *rpA_end = nnzA;
        *rpU_end = tot - nnzA;
    }
}

// ---------------- pass 2: scatter into bucket-partitioned tmp ----------------
__global__ __launch_bounds__(TP) void pass2_scatter(
    const float* __restrict__ va, const int* __restrict__ ra, const int* __restrict__ ia, int na,
    const float* __restrict__ vu, const int* __restrict__ ru, const int* __restrict__ iu, int nu,
    const uint32_t* __restrict__ map, const int* __restrict__ scanned,
    uint2* __restrict__ tmp, int nblk, int nbA, int nbTot)
{
    __shared__ int cur[NBMAX];
    const int blk = blockIdx.x;
    for (int i = threadIdx.x; i < nbTot; i += TP)
        cur[i] = scanned[(size_t)i * nblk + blk];
    __syncthreads();
    const int base = blk * (TP * EP);
    const int n = na + nu;
    for (int i = 0; i < EP; ++i) {
        int e = base + i * TP + threadIdx.x;
        if (e < na) {
            int r = __builtin_nontemporal_load(ra + e);
            int p = atomicAdd(&cur[r >> BSHIFT], 1);
            uint32_t key = ((uint32_t)(r & 255) << 17) | (uint32_t)__builtin_nontemporal_load(ia + e);
            tmp[p] = make_uint2(key, (uint32_t)__float_as_uint(__builtin_nontemporal_load(va + e)));
        } else if (e < n) {
            int k = e - na;
            int r = __builtin_nontemporal_load(ru + k);
            if (map[r] == 0xFFFFFFFFu) continue;
            int p = atomicAdd(&cur[nbA + (r >> BSHIFT)], 1);
            uint32_t key = ((uint32_t)(r & 255) << 17) | (uint32_t)__builtin_nontemporal_load(iu + k);
            tmp[p] = make_uint2(key, (uint32_t)__float_as_uint(__builtin_nontemporal_load(vu + k)));
        }
    }
}

// ---------------- per-bucket fine sort -> packed 4B CSR + rowptr ----------------
__global__ __launch_bounds__(1024) void bucket_sort(const uint2* __restrict__ tmp,
                                                    const int* __restrict__ bases,
                                                    uint32_t* __restrict__ pk,
                                                    int* __restrict__ rpA, int* __restrict__ rpU,
                                                    int nbA, int nnzA, int nItems, int nUsers) {
    __shared__ int h[256];
    __shared__ int cur[256];
    const int t = threadIdx.x;
    const int b = blockIdx.x;
    const int lo = bases[b], hi = bases[b + 1];
    const bool isU = (b >= nbA);
    const int rowbase = (isU ? (b - nbA) : b) << BSHIFT;

    if (t < 256) h[t] = 0;
    __syncthreads();
    for (int i = lo + t; i < hi; i += 1024)
        atomicAdd(&h[tmp[i].x >> 17], 1);
    __syncthreads();
    int cnt = (t < 256) ? h[t] : 0;
    for (int off = 1; off < 256; off <<= 1) {
        int u = (t < 256 && t >= off) ? h[t - off] : 0;
        __syncthreads();
        if (t < 256) h[t] += u;
        __syncthreads();
    }
    if (t < 256) {
        int gpos = lo + h[t] - cnt;
        int row = rowbase + t;
        if (isU) { if (row < nUsers) rpU[row] = gpos - nnzA; }
        else     { if (row < nItems) rpA[row] = gpos; }
        cur[t] = gpos;
    }
    __syncthreads();
    for (int i = lo + t; i < hi; i += 1024) {
        uint2 e = tmp[i];
        int rl = (int)(e.x >> 17);
        uint32_t col = e.x & 0x1FFFFu;
        int p = atomicAdd(&cur[rl], 1);
        float v = __uint_as_float(e.y);
        uint32_t q = (uint32_t)(v * 32767.0f + 0.5f);
        if (q > 32767u) q = 32767u;
        pk[p] = (col << 15) | q;
    }
}

// ---------------- sliced CSR SpMM: 8 groups x 8 lanes, slice-resident in L2 ----------------
#define DECODE(w, v, c) { v = (float)((w) & 0x7FFFu) * (1.0f/32767.0f); c = (int)((w) >> 15); }

__global__ __launch_bounds__(256) void spmm_sl(
    const uint32_t* __restrict__ pk, const int* __restrict__ rowptr,
    const uint32_t* __restrict__ xs,     // slice-major [NSLICE][rows][SLW]
    uint32_t* __restrict__ outs,         // slice-major out (L1/L2) or null (L3)
    const float2* __restrict__ emb2,     // row-major fp32 (50 float2/row), L3 only
    const uint32_t* __restrict__ x1s, const uint32_t* __restrict__ x2s,
    float2* __restrict__ total2, uint32_t* __restrict__ totu,  // row-major, L3
    int nrows)
{
    const int slice = blockIdx.y;
    const int row = blockIdx.x * 4 + (threadIdx.x >> 6);
    if (row >= nrows) return;
    const int lane = threadIdx.x & 63;
    const int g = lane >> 3, j = lane & 7;
    const size_t sb = (size_t)slice * nrows * SLW;
    const int start = rowptr[row], end = rowptr[row + 1];
    float a0 = 0.f, a1 = 0.f;
    for (int base = start; base < end; base += 64) {
        const int nc = min(64, end - base);
        uint32_t w = 0;
        if (lane < nc) w = __builtin_nontemporal_load(pk + base + lane);
        float myv; int myc;
        DECODE(w, myv, myc);
        for (int t = 0; t < nc; t += 8) {
            float v = __shfl(myv, t + g);      // garbage lanes decode to v=0
            int   c = __shfl(myc, t + g);
            uint32_t p = xs[sb + (size_t)c * SLW + j];
            a0 = fmaf(v, bflo(p), a0);
            a1 = fmaf(v, bfhi(p), a1);
        }
    }
    a0 += __shfl_xor(a0, 8);  a1 += __shfl_xor(a1, 8);
    a0 += __shfl_xor(a0, 16); a1 += __shfl_xor(a1, 16);
    a0 += __shfl_xor(a0, 32); a1 += __shfl_xor(a1, 32);
    if (lane < SLW) {
        if (outs) {
            outs[sb + (size_t)row * SLW + lane] = pack_bf16(a0, a1);
        } else {
            const int d0 = slice * 16 + lane * 2;
            if (d0 < EMB) {
                const size_t ri = (size_t)row * 50 + slice * SLW + lane;
                float2 e = emb2[ri];
                uint32_t w1 = x1s[sb + (size_t)row * SLW + lane];
                uint32_t w2 = x2s[sb + (size_t)row * SLW + lane];
                float t0 = e.x + bflo(w1) + bflo(w2) + a0;
                float t1 = e.y + bfhi(w1) + bfhi(w2) + a1;
                total2[ri] = make_float2(t0, t1);
                totu[ri] = pack_bf16(t0, t1);
            }
        }
    }
}

// ---------------- batch-user CSR SpMM (row-major operand, round-8 layout) ----------------
#define FMA2(vv, pp) { a0 = fmaf((vv), bflo((pp).x), a0); a1 = fmaf((vv), bfhi((pp).x), a1); \
                       a2 = fmaf((vv), bflo((pp).y), a2); a3 = fmaf((vv), bfhi((pp).y), a3); }

__global__ __launch_bounds__(256) void spmm_batch_pk(
    const uint32_t* __restrict__ pk, const int* __restrict__ rowptr,
    const int* __restrict__ user, const uint2* __restrict__ xbf2,
    float4* __restrict__ out4, int batch)
{
    const int wid = (blockIdx.x * blockDim.x + threadIdx.x) >> 6;
    const int lane = threadIdx.x & 63;
    if (wid >= batch) return;
    const int half = lane >> 5;
    const int l = lane & 31;
    const int row = user[wid];
    const int start = rowptr[row], end = rowptr[row + 1];
    float a0 = 0.f, a1 = 0.f, a2 = 0.f, a3 = 0.f;
    for (int base = start; base < end; base += 64) {
        const int nc = min(64, end - base);
        uint32_t w = 0;
        if (lane < nc) w = __builtin_nontemporal_load(pk + base + lane);
        float myv; int myc;
        DECODE(w, myv, myc);
        int t = 0;
        for (; t + 8 <= nc; t += 8) {
            float v0 = __shfl(myv, t + half),     v1 = __shfl(myv, t + 2 + half);
            float v2 = __shfl(myv, t + 4 + half), v3 = __shfl(myv, t + 6 + half);
            int   c0 = __shfl(myc, t + half),     c1 = __shfl(myc, t + 2 + half);
            int   c2 = __shfl(myc, t + 4 + half), c3 = __shfl(myc, t + 6 + half);
            uint2 p0 = make_uint2(0u,0u), p1 = make_uint2(0u,0u);
            uint2 p2 = make_uint2(0u,0u), p3 = make_uint2(0u,0u);
            if (l < HW2) {
                p0 = xbf2[(size_t)c0 * HW2 + l];
                p1 = xbf2[(size_t)c1 * HW2 + l];
                p2 = xbf2[(size_t)c2 * HW2 + l];
                p3 = xbf2[(size_t)c3 * HW2 + l];
            }
            FMA2(v0, p0); FMA2(v1, p1); FMA2(v2, p2); FMA2(v3, p3);
        }
        for (; t < nc; t += 2) {
            int tt = min(t + half, nc - 1);
            float v0 = __shfl(myv, tt);
            int   c0 = __shfl(myc, tt);
            if (t + half >= nc) v0 = 0.f;
            uint2 p0 = make_uint2(0u,0u);
            if (l < HW2) p0 = xbf2[(size_t)c0 * HW2 + l];
            FMA2(v0, p0);
        }
    }
    a0 += __shfl_xor(a0, 32); a1 += __shfl_xor(a1, 32);
    a2 += __shfl_xor(a2, 32); a3 += __shfl_xor(a3, 32);
    if (lane < HW2) out4[(size_t)wid * HW2 + lane] = make_float4(a0, a1, a2, a3);
}

// ---------------- fallback (round-1) kernels ----------------
__global__ void spmm_scatter(const float* __restrict__ vals, const int* __restrict__ rows,
                             const int* __restrict__ cols, const float* __restrict__ x,
                             float* __restrict__ out, int nnz) {
    long long t = (long long)blockIdx.x * blockDim.x + threadIdx.x;
    int e = (int)(t / V4_PER_ROW);
    int c = (int)(t % V4_PER_ROW);
    if (e >= nnz) return;
    int col = cols[e]; int row = rows[e]; float v = vals[e];
    const float4 g = *(const float4*)(x + (size_t)col * EMB + c * 4);
    float* o = out + (size_t)row * EMB + c * 4;
    atomicAdd(o + 0, v * g.x); atomicAdd(o + 1, v * g.y);
    atomicAdd(o + 2, v * g.z); atomicAdd(o + 3, v * g.w);
}
__global__ void add_inplace(float* __restrict__ acc, const float* __restrict__ x, int n4) {
    int i = blockIdx.x * blockDim.x + threadIdx.x;
    if (i < n4) {
        float4 a = ((const float4*)acc)[i];
        const float4 b = ((const float4*)x)[i];
        a.x += b.x; a.y += b.y; a.z += b.z; a.w += b.w;
        ((float4*)acc)[i] = a;
    }
}
__global__ void gather_rows(const float* __restrict__ src, const int* __restrict__ idx,
                            float* __restrict__ out, int nrows) {
    int t = blockIdx.x * blockDim.x + threadIdx.x;
    int r = t / V4_PER_ROW, c = t % V4_PER_ROW;
    if (r >= nrows) return;
    int s = idx[r];
    *(float4*)(out + (size_t)r * EMB + c * 4) = *(const float4*)(src + (size_t)s * EMB + c * 4);
}

// ---------------- launch ----------------
static inline size_t align256(size_t x) { return (x + 255) & ~(size_t)255; }

extern "C" void kernel_launch(void* const* d_in, const int* in_sizes, int n_in,
                              void* d_out, int out_size, void* d_ws, size_t ws_size,
                              hipStream_t stream) {
    const float* adj_vals  = (const float*)d_in[0];
    const float* u_vals    = (const float*)d_in[1];
    const float* embedding = (const float*)d_in[2];
    const int*   adj_rows  = (const int*)d_in[4];
    const int*   adj_cols  = (const int*)d_in[5];
    const int*   u_rows    = (const int*)d_in[6];
    const int*   u_cols    = (const int*)d_in[7];
    const int*   user      = (const int*)d_in[8];

    const int NNZ_A   = in_sizes[0];
    const int NNZ_U   = in_sizes[1];
    const int N_ITEMS = in_sizes[2] / EMB;
    const int N_USERS = in_sizes[3] / EMB;
    const int BATCH   = in_sizes[8];

    const int NB_A = (N_ITEMS + 255) >> BSHIFT;
    const int NB_U = (N_USERS + 255) >> BSHIFT;
    const int NB_TOT = NB_A + NB_U;

    const int NNZ_T = NNZ_A + NNZ_U;
    const int nblk = (NNZ_T + TP * EP - 1) / (TP * EP);
    const long long nScan = (long long)NB_TOT * nblk;
    const int nsb = (int)((nScan + SCAN_T * SCAN_E - 1) / (SCAN_T * SCAN_E));

    float* total    = (float*)d_out;
    float* out_user = total + (size_t)N_ITEMS * EMB;

    const size_t sliceWords = (size_t)N_ITEMS * NSLICE * SLW;  // dwords per slice-major buffer

    // ---- workspace layout ----
    size_t off = 0;
    char* ws = (char*)d_ws;
    #define WS_ALLOC(name, bytes) char* name = ws + off; off += align256(bytes)
    WS_ALLOC(p_x12,     2 * sliceWords * 4);             // x1s|x2s (aliased by tmp pre-L1)
    WS_ALLOC(p_ebf,     sliceWords * 4);                 // embs (slice-major) -> totbf (row-major)
    WS_ALLOC(p_pk,      (size_t)NNZ_T * 4);              // packed CSR (A then U)
    WS_ALLOC(p_rpA,     ((size_t)N_ITEMS + 1) * 4);
    WS_ALLOC(p_rpU,     ((size_t)N_USERS + 1) * 4);
    WS_ALLOC(p_map,     (size_t)N_USERS * 4);
    WS_ALLOC(p_countsT, (size_t)nScan * 4);
    WS_ALLOC(p_sums,    256 * 4);
    WS_ALLOC(p_total,   4);
    WS_ALLOC(p_bases,   ((size_t)NB_TOT + 1) * 4);
    #undef WS_ALLOC
    const size_t tmpBytes = (size_t)NNZ_T * 8;

    if (ws_size >= off && tmpBytes <= 2 * sliceWords * 4 && NB_TOT <= NBMAX && nsb <= 256
        && N_ITEMS <= (1 << 17) && N_USERS <= (1 << 17)) {
        uint32_t* x1s   = (uint32_t*)p_x12;
        uint32_t* x2s   = x1s + sliceWords;
        uint2*    tmp   = (uint2*)p_x12;                 // dead before L1 writes x1s
        uint32_t* embs  = (uint32_t*)p_ebf;              // slice-major bf16 embedding
        uint32_t* totu  = (uint32_t*)p_ebf;              // row-major bf16 total (L3 output)
        uint32_t* pk    = (uint32_t*)p_pk;
        int* rpA = (int*)p_rpA;
        int* rpU = (int*)p_rpU;
        uint32_t* map = (uint32_t*)p_map;
        int* countsT = (int*)p_countsT;
        int* sums    = (int*)p_sums;
        int* totalN  = (int*)p_total;
        int* bases   = (int*)p_bases;

        hipMemsetAsync(map, 0xFF, (size_t)N_USERS * 4, stream);
        map_build<<<(BATCH + 255) / 256, 256, 0, stream>>>(user, map, BATCH);

        // embedding -> slice-major packed bf16
        {
            dim3 g((N_ITEMS * SLW + 255) / 256, NSLICE);
            convert_sl<<<g, 256, 0, stream>>>((const float2*)embedding, embs, N_ITEMS);
        }

        pass1_count<<<nblk, TP, 0, stream>>>(adj_rows, NNZ_A, u_rows, NNZ_U, map,
                                             countsT, nblk, NB_A, NB_TOT);
        scan_blocks<<<nsb, SCAN_T, 0, stream>>>(countsT, countsT, sums, (int)nScan);
        scan_mid<<<1, 256, 0, stream>>>(sums, nsb, totalN);
        scan_fixup<<<nsb, SCAN_T, 0, stream>>>(countsT, sums, (int)nScan);
        extract_bases<<<(NB_TOT + 255) / 256, 256, 0, stream>>>(countsT, nblk, NB_TOT, totalN,
                                                                bases, rpA + N_ITEMS, NNZ_A,
                                                                rpU + N_USERS);
        pass2_scatter<<<nblk, TP, 0, stream>>>(adj_vals, adj_rows, adj_cols, NNZ_A,
                                               u_vals, u_rows, u_cols, NNZ_U,
                                               map, countsT, tmp, nblk, NB_A, NB_TOT);
        bucket_sort<<<NB_TOT, 1024, 0, stream>>>(tmp, bases, pk, rpA, rpU,
                                                 NB_A, NNZ_A, N_ITEMS, N_USERS);

        const int bps = (N_ITEMS + 3) / 4;   // blocks per slice (4 rows/block)
        dim3 gridA(bps, NSLICE);
        // L1: x1 = A emb   (slice-major out)
        spmm_sl<<<gridA, 256, 0, stream>>>(pk, rpA, embs, x1s,
                                           nullptr, nullptr, nullptr, nullptr, nullptr, N_ITEMS);
        // L2: x2 = A x1
        spmm_sl<<<gridA, 256, 0, stream>>>(pk, rpA, x1s, x2s,
                                           nullptr, nullptr, nullptr, nullptr, nullptr, N_ITEMS);
        // L3: acc = A x2 ; total = emb + x1 + x2 + acc (row-major fp32 + bf16)
        spmm_sl<<<gridA, 256, 0, stream>>>(pk, rpA, x2s, nullptr,
                                           (const float2*)embedding, x1s, x2s,
                                           (float2*)total, totu, N_ITEMS);
        // batch user rows from row-major totu
        spmm_batch_pk<<<(BATCH + 3) / 4, 256, 0, stream>>>(pk + NNZ_A, rpU, user,
                                                           (const uint2*)totu,
                                                           (float4*)out_user, BATCH);
    } else {
        // ---- fallback: round-1 atomic path ----
        const size_t itemBytes = (size_t)N_ITEMS * EMB * sizeof(float);
        float* buf0 = (float*)d_ws;
        float* buf1 = buf0 + (size_t)N_ITEMS * EMB;
        float* user_all = buf1;
        const size_t userBytes = (size_t)N_USERS * EMB * sizeof(float);

        hipMemcpyAsync(total, embedding, itemBytes, hipMemcpyDeviceToDevice, stream);
        const int blkA = (NNZ_A * V4_PER_ROW + 255) / 256;
        const int blkU = (NNZ_U * V4_PER_ROW + 255) / 256;
        const int n4 = N_ITEMS * EMB / 4;
        const int blkAdd = (n4 + 255) / 256;

        hipMemsetAsync(buf0, 0, itemBytes, stream);
        spmm_scatter<<<blkA, 256, 0, stream>>>(adj_vals, adj_rows, adj_cols, embedding, buf0, NNZ_A);
        add_inplace<<<blkAdd, 256, 0, stream>>>(total, buf0, n4);
        hipMemsetAsync(buf1, 0, itemBytes, stream);
        spmm_scatter<<<blkA, 256, 0, stream>>>(adj_vals, adj_rows, adj_cols, buf0, buf1, NNZ_A);
        add_inplace<<<blkAdd, 256, 0, stream>>>(total, buf1, n4);
        hipMemsetAsync(buf0, 0, itemBytes, stream);
        spmm_scatter<<<blkA, 256, 0, stream>>>(adj_vals, adj_rows, adj_cols, buf1, buf0, NNZ_A);
        add_inplace<<<blkAdd, 256, 0, stream>>>(total, buf0, n4);
        hipMemsetAsync(user_all, 0, userBytes, stream);
        spmm_scatter<<<blkU, 256, 0, stream>>>(u_vals, u_rows, u_cols, total, user_all, NNZ_U);
        gather_rows<<<(BATCH * V4_PER_ROW + 255) / 256, 256, 0, stream>>>(user_all, user, out_user, BATCH);
    }
}

// Round 10
// 567.868 us; speedup vs baseline: 1.9283x; 1.9283x over previous
//
#include <hip/hip_runtime.h>
#include <stdint.h>

#define EMB 100
#define HW2 25           // uint2 (4 bf16) per row
#define V4_PER_ROW 25
#define BSHIFT 8         // 256 rows per bucket
#define NBMAX 1024
#define TP 256
#define EP 32

#define SCAN_T 256
#define SCAN_E 32

// ---------------- bf16 helpers ----------------
static __device__ __forceinline__ uint32_t pack_bf16(float a, float b) {
    uint32_t ua = __float_as_uint(a);
    uint32_t ub = __float_as_uint(b);
    ua = (ua + 0x7FFFu + ((ua >> 16) & 1u)) >> 16;
    ub = (ub + 0x7FFFu + ((ub >> 16) & 1u)) >> 16;
    return ua | (ub << 16);
}
static __device__ __forceinline__ float bflo(uint32_t p) { return __uint_as_float(p << 16); }
static __device__ __forceinline__ float bfhi(uint32_t p) { return __uint_as_float(p & 0xFFFF0000u); }

__global__ void convert_bf16(const float2* __restrict__ x, uint32_t* __restrict__ xbf, int nwords) {
    for (int i = blockIdx.x * blockDim.x + threadIdx.x; i < nwords; i += gridDim.x * blockDim.x) {
        float2 v = x[i];
        xbf[i] = pack_bf16(v.x, v.y);
    }
}

// ---------------- batch-user map ----------------
__global__ void map_build(const int* __restrict__ user, uint32_t* __restrict__ map, int batch) {
    int i = blockIdx.x * blockDim.x + threadIdx.x;
    if (i < batch) atomicMin(&map[user[i]], (uint32_t)i);
}

// ---------------- pass 1: per-(block,bucket) counts, no global atomics ----------------
__global__ __launch_bounds__(TP) void pass1_count(
    const int* __restrict__ ra, int na, const int* __restrict__ ru, int nu,
    const uint32_t* __restrict__ map, int* __restrict__ countsT,
    int nblk, int nbA, int nbTot)
{
    __shared__ int lc[NBMAX];
    const int blk = blockIdx.x;
    for (int i = threadIdx.x; i < nbTot; i += TP) lc[i] = 0;
    __syncthreads();
    const int base = blk * (TP * EP);
    const int n = na + nu;
    for (int i = 0; i < EP; ++i) {
        int e = base + i * TP + threadIdx.x;
        int b = -1;
        if (e < na) {
            b = __builtin_nontemporal_load(ra + e) >> BSHIFT;
        } else if (e < n) {
            int r = __builtin_nontemporal_load(ru + (e - na));
            if (map[r] != 0xFFFFFFFFu) b = nbA + (r >> BSHIFT);
        }
        if (b >= 0) atomicAdd(&lc[b], 1);
    }
    __syncthreads();
    for (int i = threadIdx.x; i < nbTot; i += TP)
        countsT[(size_t)i * nblk + blk] = lc[i];
}

// ---------------- 3-phase exclusive scan over countsT ----------------
__global__ void scan_blocks(const int* __restrict__ in, int* __restrict__ out,
                            int* __restrict__ sums, int n) {
    __shared__ int smem[SCAN_T];
    const int b = blockIdx.x, tid = threadIdx.x;
    const int base = b * SCAN_T * SCAN_E + tid * SCAN_E;
    int loc[SCAN_E];
    int s = 0;
    for (int i = 0; i < SCAN_E; ++i) {
        int idx = base + i;
        int v = (idx < n) ? in[idx] : 0;
        loc[i] = s; s += v;
    }
    smem[tid] = s; __syncthreads();
    for (int off = 1; off < SCAN_T; off <<= 1) {
        int v = (tid >= off) ? smem[tid - off] : 0;
        __syncthreads();
        smem[tid] += v;
        __syncthreads();
    }
    int pre = (tid == 0) ? 0 : smem[tid - 1];
    if (tid == SCAN_T - 1) sums[b] = smem[tid];
    for (int i = 0; i < SCAN_E; ++i) {
        int idx = base + i;
        if (idx < n) out[idx] = pre + loc[i];
    }
}

__global__ void scan_mid(int* __restrict__ sums, int nb, int* __restrict__ total_out) {
    __shared__ int sh[256];
    const int t = threadIdx.x;
    int v = (t < nb) ? sums[t] : 0;
    sh[t] = v; __syncthreads();
    for (int off = 1; off < 256; off <<= 1) {
        int u = (t >= off) ? sh[t - off] : 0;
        __syncthreads();
        sh[t] += u;
        __syncthreads();
    }
    if (t < nb) sums[t] = sh[t];
    if (t == 255) *total_out = sh[255];
}

__global__ void scan_fixup(int* __restrict__ out, const int* __restrict__ sums, int n) {
    const int b = blockIdx.x;
    if (b == 0) return;
    const int add = sums[b - 1];
    const int base = b * SCAN_T * SCAN_E + threadIdx.x * SCAN_E;
    for (int i = 0; i < SCAN_E; ++i) {
        int idx = base + i;
        if (idx < n) out[idx] += add;
    }
}

__global__ void extract_bases(const int* __restrict__ scanned, int nblk, int nbTot,
                              const int* __restrict__ total, int* __restrict__ bases,
                              int* __restrict__ rpA_end, int nnzA, int* __restrict__ rpU_end) {
    int t = blockIdx.x * blockDim.x + threadIdx.x;
    if (t < nbTot) bases[t] = scanned[(size_t)t * nblk];
    if (t == 0) {
        int tot = *total;
        bases[nbTot] = tot;
        *rpA_end = nnzA;
        *rpU_end = tot - nnzA;
    }
}

// ---------------- pass 2: scatter into bucket-partitioned tmp ----------------
__global__ __launch_bounds__(TP) void pass2_scatter(
    const float* __restrict__ va, const int* __restrict__ ra, const int* __restrict__ ia, int na,
    const float* __restrict__ vu, const int* __restrict__ ru, const int* __restrict__ iu, int nu,
    const uint32_t* __restrict__ map, const int* __restrict__ scanned,
    uint2* __restrict__ tmp, int nblk, int nbA, int nbTot)
{
    __shared__ int cur[NBMAX];
    const int blk = blockIdx.x;
    for (int i = threadIdx.x; i < nbTot; i += TP)
        cur[i] = scanned[(size_t)i * nblk + blk];
    __syncthreads();
    const int base = blk * (TP * EP);
    const int n = na + nu;
    for (int i = 0; i < EP; ++i) {
        int e = base + i * TP + threadIdx.x;
        if (e < na) {
            int r = __builtin_nontemporal_load(ra + e);
            int p = atomicAdd(&cur[r >> BSHIFT], 1);
            uint32_t key = ((uint32_t)(r & 255) << 17) | (uint32_t)__builtin_nontemporal_load(ia + e);
            tmp[p] = make_uint2(key, (uint32_t)__float_as_uint(__builtin_nontemporal_load(va + e)));
        } else if (e < n) {
            int k = e - na;
            int r = __builtin_nontemporal_load(ru + k);
            if (map[r] == 0xFFFFFFFFu) continue;
            int p = atomicAdd(&cur[nbA + (r >> BSHIFT)], 1);
            uint32_t key = ((uint32_t)(r & 255) << 17) | (uint32_t)__builtin_nontemporal_load(iu + k);
            tmp[p] = make_uint2(key, (uint32_t)__float_as_uint(__builtin_nontemporal_load(vu + k)));
        }
    }
}

// ---------------- per-bucket fine sort -> packed 4B CSR + rowptr ----------------
__global__ __launch_bounds__(1024) void bucket_sort(const uint2* __restrict__ tmp,
                                                    const int* __restrict__ bases,
                                                    uint32_t* __restrict__ pk,
                                                    int* __restrict__ rpA, int* __restrict__ rpU,
                                                    int nbA, int nnzA, int nItems, int nUsers) {
    __shared__ int h[256];
    __shared__ int cur[256];
    const int t = threadIdx.x;
    const int b = blockIdx.x;
    const int lo = bases[b], hi = bases[b + 1];
    const bool isU = (b >= nbA);
    const int rowbase = (isU ? (b - nbA) : b) << BSHIFT;

    if (t < 256) h[t] = 0;
    __syncthreads();
    for (int i = lo + t; i < hi; i += 1024)
        atomicAdd(&h[tmp[i].x >> 17], 1);
    __syncthreads();
    int cnt = (t < 256) ? h[t] : 0;
    for (int off = 1; off < 256; off <<= 1) {
        int u = (t < 256 && t >= off) ? h[t - off] : 0;
        __syncthreads();
        if (t < 256) h[t] += u;
        __syncthreads();
    }
    if (t < 256) {
        int gpos = lo + h[t] - cnt;   // exclusive
        int row = rowbase + t;
        if (isU) { if (row < nUsers) rpU[row] = gpos - nnzA; }
        else     { if (row < nItems) rpA[row] = gpos; }
        cur[t] = gpos;
    }
    __syncthreads();
    for (int i = lo + t; i < hi; i += 1024) {
        uint2 e = tmp[i];
        int rl = (int)(e.x >> 17);
        uint32_t col = e.x & 0x1FFFFu;
        int p = atomicAdd(&cur[rl], 1);
        float v = __uint_as_float(e.y);
        uint32_t q = (uint32_t)(v * 32767.0f + 0.5f);
        if (q > 32767u) q = 32767u;
        pk[p] = (col << 15) | q;
    }
}

// ---------------- CSR SpMM: wave-per-row, 16-nnz deep (8 uint2 loads in flight) ----------------
#define DECODE(w, v, c) { v = (float)((w) & 0x7FFFu) * (1.0f/32767.0f); c = (int)((w) >> 15); }

#define FMA2(vv, pp) { a0 = fmaf((vv), bflo((pp).x), a0); a1 = fmaf((vv), bfhi((pp).x), a1); \
                       a2 = fmaf((vv), bflo((pp).y), a2); a3 = fmaf((vv), bfhi((pp).y), a3); }

__global__ __launch_bounds__(256, 8) void spmm_pk(
    const uint32_t* __restrict__ pk, const int* __restrict__ rowptr,
    const uint2* __restrict__ xbf2, uint2* __restrict__ outbf2,
    const float4* __restrict__ emb4, const uint2* __restrict__ x1bf2,
    const uint2* __restrict__ x2bf2, float4* __restrict__ total4,
    uint2* __restrict__ totbf2, int nrows)
{
    const int wid = (blockIdx.x * blockDim.x + threadIdx.x) >> 6;
    const int lane = threadIdx.x & 63;
    if (wid >= nrows) return;
    const int half = lane >> 5;        // which nnz of the pair
    const int l = lane & 31;           // word index, active l<25
    const int start = rowptr[wid], end = rowptr[wid + 1];
    float a0 = 0.f, a1 = 0.f, a2 = 0.f, a3 = 0.f;
    for (int base = start; base < end; base += 64) {
        const int nc = min(64, end - base);
        uint32_t w = 0;
        if (lane < nc) w = __builtin_nontemporal_load(pk + base + lane);
        float myv; int myc;
        DECODE(w, myv, myc);
        int t = 0;
        for (; t + 16 <= nc; t += 16) {
            float v_[8]; int c_[8];
            #pragma unroll
            for (int k = 0; k < 8; ++k) {
                v_[k] = __shfl(myv, t + 2 * k + half);
                c_[k] = __shfl(myc, t + 2 * k + half);
            }
            uint2 p_[8];
            #pragma unroll
            for (int k = 0; k < 8; ++k) p_[k] = make_uint2(0u, 0u);
            if (l < HW2) {
                #pragma unroll
                for (int k = 0; k < 8; ++k) p_[k] = xbf2[(size_t)c_[k] * HW2 + l];
            }
            #pragma unroll
            for (int k = 0; k < 8; ++k) { FMA2(v_[k], p_[k]); }
        }
        for (; t + 8 <= nc; t += 8) {
            float v0 = __shfl(myv, t + half),     v1 = __shfl(myv, t + 2 + half);
            float v2 = __shfl(myv, t + 4 + half), v3 = __shfl(myv, t + 6 + half);
            int   c0 = __shfl(myc, t + half),     c1 = __shfl(myc, t + 2 + half);
            int   c2 = __shfl(myc, t + 4 + half), c3 = __shfl(myc, t + 6 + half);
            uint2 p0 = make_uint2(0u,0u), p1 = make_uint2(0u,0u);
            uint2 p2 = make_uint2(0u,0u), p3 = make_uint2(0u,0u);
            if (l < HW2) {
                p0 = xbf2[(size_t)c0 * HW2 + l];
                p1 = xbf2[(size_t)c1 * HW2 + l];
                p2 = xbf2[(size_t)c2 * HW2 + l];
                p3 = xbf2[(size_t)c3 * HW2 + l];
            }
            FMA2(v0, p0); FMA2(v1, p1); FMA2(v2, p2); FMA2(v3, p3);
        }
        for (; t < nc; t += 2) {
            int tt = min(t + half, nc - 1);
            float v0 = __shfl(myv, tt);
            int   c0 = __shfl(myc, tt);
            if (t + half >= nc) v0 = 0.f;
            uint2 p0 = make_uint2(0u,0u);
            if (l < HW2) p0 = xbf2[(size_t)c0 * HW2 + l];
            FMA2(v0, p0);
        }
    }
    a0 += __shfl_xor(a0, 32); a1 += __shfl_xor(a1, 32);
    a2 += __shfl_xor(a2, 32); a3 += __shfl_xor(a3, 32);
    if (lane < HW2) {
        const size_t widx = (size_t)wid * HW2 + lane;
        if (outbf2) {
            outbf2[widx] = make_uint2(pack_bf16(a0, a1), pack_bf16(a2, a3));
        } else {
            float4 e = emb4[widx];
            uint2 w1 = x1bf2[widx], w2 = x2bf2[widx];
            float t0 = e.x + bflo(w1.x) + bflo(w2.x) + a0;
            float t1 = e.y + bfhi(w1.x) + bfhi(w2.x) + a1;
            float t2 = e.z + bflo(w1.y) + bflo(w2.y) + a2;
            float t3 = e.w + bfhi(w1.y) + bfhi(w2.y) + a3;
            total4[widx] = make_float4(t0, t1, t2, t3);
            totbf2[widx] = make_uint2(pack_bf16(t0, t1), pack_bf16(t2, t3));
        }
    }
}

__global__ __launch_bounds__(256, 8) void spmm_batch_pk(
    const uint32_t* __restrict__ pk, const int* __restrict__ rowptr,
    const int* __restrict__ user, const uint2* __restrict__ xbf2,
    float4* __restrict__ out4, int batch)
{
    const int wid = (blockIdx.x * blockDim.x + threadIdx.x) >> 6;
    const int lane = threadIdx.x & 63;
    if (wid >= batch) return;
    const int half = lane >> 5;
    const int l = lane & 31;
    const int row = user[wid];
    const int start = rowptr[row], end = rowptr[row + 1];
    float a0 = 0.f, a1 = 0.f, a2 = 0.f, a3 = 0.f;
    for (int base = start; base < end; base += 64) {
        const int nc = min(64, end - base);
        uint32_t w = 0;
        if (lane < nc) w = __builtin_nontemporal_load(pk + base + lane);
        float myv; int myc;
        DECODE(w, myv, myc);
        int t = 0;
        for (; t + 16 <= nc; t += 16) {
            float v_[8]; int c_[8];
            #pragma unroll
            for (int k = 0; k < 8; ++k) {
                v_[k] = __shfl(myv, t + 2 * k + half);
                c_[k] = __shfl(myc, t + 2 * k + half);
            }
            uint2 p_[8];
            #pragma unroll
            for (int k = 0; k < 8; ++k) p_[k] = make_uint2(0u, 0u);
            if (l < HW2) {
                #pragma unroll
                for (int k = 0; k < 8; ++k) p_[k] = xbf2[(size_t)c_[k] * HW2 + l];
            }
            #pragma unroll
            for (int k = 0; k < 8; ++k) { FMA2(v_[k], p_[k]); }
        }
        for (; t + 8 <= nc; t += 8) {
            float v0 = __shfl(myv, t + half),     v1 = __shfl(myv, t + 2 + half);
            float v2 = __shfl(myv, t + 4 + half), v3 = __shfl(myv, t + 6 + half);
            int   c0 = __shfl(myc, t + half),     c1 = __shfl(myc, t + 2 + half);
            int   c2 = __shfl(myc, t + 4 + half), c3 = __shfl(myc, t + 6 + half);
            uint2 p0 = make_uint2(0u,0u), p1 = make_uint2(0u,0u);
            uint2 p2 = make_uint2(0u,0u), p3 = make_uint2(0u,0u);
            if (l < HW2) {
                p0 = xbf2[(size_t)c0 * HW2 + l];
                p1 = xbf2[(size_t)c1 * HW2 + l];
                p2 = xbf2[(size_t)c2 * HW2 + l];
                p3 = xbf2[(size_t)c3 * HW2 + l];
            }
            FMA2(v0, p0); FMA2(v1, p1); FMA2(v2, p2); FMA2(v3, p3);
        }
        for (; t < nc; t += 2) {
            int tt = min(t + half, nc - 1);
            float v0 = __shfl(myv, tt);
            int   c0 = __shfl(myc, tt);
            if (t + half >= nc) v0 = 0.f;
            uint2 p0 = make_uint2(0u,0u);
            if (l < HW2) p0 = xbf2[(size_t)c0 * HW2 + l];
            FMA2(v0, p0);
        }
    }
    a0 += __shfl_xor(a0, 32); a1 += __shfl_xor(a1, 32);
    a2 += __shfl_xor(a2, 32); a3 += __shfl_xor(a3, 32);
    if (lane < HW2) out4[(size_t)wid * HW2 + lane] = make_float4(a0, a1, a2, a3);
}

// ---------------- fallback (round-1) kernels ----------------
__global__ void spmm_scatter(const float* __restrict__ vals, const int* __restrict__ rows,
                             const int* __restrict__ cols, const float* __restrict__ x,
                             float* __restrict__ out, int nnz) {
    long long t = (long long)blockIdx.x * blockDim.x + threadIdx.x;
    int e = (int)(t / V4_PER_ROW);
    int c = (int)(t % V4_PER_ROW);
    if (e >= nnz) return;
    int col = cols[e]; int row = rows[e]; float v = vals[e];
    const float4 g = *(const float4*)(x + (size_t)col * EMB + c * 4);
    float* o = out + (size_t)row * EMB + c * 4;
    atomicAdd(o + 0, v * g.x); atomicAdd(o + 1, v * g.y);
    atomicAdd(o + 2, v * g.z); atomicAdd(o + 3, v * g.w);
}
__global__ void add_inplace(float* __restrict__ acc, const float* __restrict__ x, int n4) {
    int i = blockIdx.x * blockDim.x + threadIdx.x;
    if (i < n4) {
        float4 a = ((const float4*)acc)[i];
        const float4 b = ((const float4*)x)[i];
        a.x += b.x; a.y += b.y; a.z += b.z; a.w += b.w;
        ((float4*)acc)[i] = a;
    }
}
__global__ void gather_rows(const float* __restrict__ src, const int* __restrict__ idx,
                            float* __restrict__ out, int nrows) {
    int t = blockIdx.x * blockDim.x + threadIdx.x;
    int r = t / V4_PER_ROW, c = t % V4_PER_ROW;
    if (r >= nrows) return;
    int s = idx[r];
    *(float4*)(out + (size_t)r * EMB + c * 4) = *(const float4*)(src + (size_t)s * EMB + c * 4);
}

// ---------------- launch ----------------
static inline size_t align256(size_t x) { return (x + 255) & ~(size_t)255; }

extern "C" void kernel_launch(void* const* d_in, const int* in_sizes, int n_in,
                              void* d_out, int out_size, void* d_ws, size_t ws_size,
                              hipStream_t stream) {
    const float* adj_vals  = (const float*)d_in[0];
    const float* u_vals    = (const float*)d_in[1];
    const float* embedding = (const float*)d_in[2];
    const int*   adj_rows  = (const int*)d_in[4];
    const int*   adj_cols  = (const int*)d_in[5];
    const int*   u_rows    = (const int*)d_in[6];
    const int*   u_cols    = (const int*)d_in[7];
    const int*   user      = (const int*)d_in[8];

    const int NNZ_A   = in_sizes[0];
    const int NNZ_U   = in_sizes[1];
    const int N_ITEMS = in_sizes[2] / EMB;
    const int N_USERS = in_sizes[3] / EMB;
    const int BATCH   = in_sizes[8];

    const int NB_A = (N_ITEMS + 255) >> BSHIFT;
    const int NB_U = (N_USERS + 255) >> BSHIFT;
    const int NB_TOT = NB_A + NB_U;

    const int NNZ_T = NNZ_A + NNZ_U;
    const int nblk = (NNZ_T + TP * EP - 1) / (TP * EP);
    const long long nScan = (long long)NB_TOT * nblk;
    const int nsb = (int)((nScan + SCAN_T * SCAN_E - 1) / (SCAN_T * SCAN_E));

    float* total    = (float*)d_out;
    float* out_user = total + (size_t)N_ITEMS * EMB;

    const size_t rowWords = (size_t)N_ITEMS * 50;

    // ---- workspace layout ----
    size_t off = 0;
    char* ws = (char*)d_ws;
    #define WS_ALLOC(name, bytes) char* name = ws + off; off += align256(bytes)
    WS_ALLOC(p_r0,      2 * rowWords * 4);               // x1bf|x2bf, aliased by tmp
    WS_ALLOC(p_ebf,     rowWords * 4);                   // embbf -> totbf
    WS_ALLOC(p_pk,      (size_t)NNZ_T * 4);              // packed CSR (A then U)
    WS_ALLOC(p_rpA,     ((size_t)N_ITEMS + 1) * 4);
    WS_ALLOC(p_rpU,     ((size_t)N_USERS + 1) * 4);
    WS_ALLOC(p_map,     (size_t)N_USERS * 4);
    WS_ALLOC(p_countsT, (size_t)nScan * 4);
    WS_ALLOC(p_sums,    256 * 4);
    WS_ALLOC(p_total,   4);
    WS_ALLOC(p_bases,   ((size_t)NB_TOT + 1) * 4);
    #undef WS_ALLOC
    const size_t tmpBytes = (size_t)NNZ_T * 8;

    if (ws_size >= off && tmpBytes <= 2 * rowWords * 4 && NB_TOT <= NBMAX && nsb <= 256
        && N_ITEMS <= (1 << 17) && N_USERS <= (1 << 17)) {
        uint32_t* x1bf  = (uint32_t*)p_r0;
        uint32_t* x2bf  = (uint32_t*)(p_r0 + rowWords * 4);
        uint2*    tmp   = (uint2*)p_r0;                  // dead before x1bf is written
        uint32_t* embbf = (uint32_t*)p_ebf;
        uint32_t* totbf = (uint32_t*)p_ebf;              // embbf dead after layer 1
        uint32_t* pk    = (uint32_t*)p_pk;
        int* rpA = (int*)p_rpA;
        int* rpU = (int*)p_rpU;
        uint32_t* map = (uint32_t*)p_map;
        int* countsT = (int*)p_countsT;
        int* sums    = (int*)p_sums;
        int* totalN  = (int*)p_total;
        int* bases   = (int*)p_bases;

        hipMemsetAsync(map, 0xFF, (size_t)N_USERS * 4, stream);
        map_build<<<(BATCH + 255) / 256, 256, 0, stream>>>(user, map, BATCH);

        convert_bf16<<<2048, 256, 0, stream>>>((const float2*)embedding, embbf, (int)rowWords);

        pass1_count<<<nblk, TP, 0, stream>>>(adj_rows, NNZ_A, u_rows, NNZ_U, map,
                                             countsT, nblk, NB_A, NB_TOT);
        scan_blocks<<<nsb, SCAN_T, 0, stream>>>(countsT, countsT, sums, (int)nScan);
        scan_mid<<<1, 256, 0, stream>>>(sums, nsb, totalN);
        scan_fixup<<<nsb, SCAN_T, 0, stream>>>(countsT, sums, (int)nScan);
        extract_bases<<<(NB_TOT + 255) / 256, 256, 0, stream>>>(countsT, nblk, NB_TOT, totalN,
                                                                bases, rpA + N_ITEMS, NNZ_A,
                                                                rpU + N_USERS);
        pass2_scatter<<<nblk, TP, 0, stream>>>(adj_vals, adj_rows, adj_cols, NNZ_A,
                                               u_vals, u_rows, u_cols, NNZ_U,
                                               map, countsT, tmp, nblk, NB_A, NB_TOT);
        bucket_sort<<<NB_TOT, 1024, 0, stream>>>(tmp, bases, pk, rpA, rpU,
                                                 NB_A, NNZ_A, N_ITEMS, N_USERS);

        const int gridA = (N_ITEMS + 3) / 4;   // 4 waves per 256-thread block
        // L1: x1 = A emb
        spmm_pk<<<gridA, 256, 0, stream>>>(pk, rpA, (const uint2*)embbf, (uint2*)x1bf,
                                           nullptr, nullptr, nullptr, nullptr, nullptr, N_ITEMS);
        // L2: x2 = A x1
        spmm_pk<<<gridA, 256, 0, stream>>>(pk, rpA, (const uint2*)x1bf, (uint2*)x2bf,
                                           nullptr, nullptr, nullptr, nullptr, nullptr, N_ITEMS);
        // L3: acc = A x2 ; total = emb + x1 + x2 + acc ; totbf = pack(total)
        spmm_pk<<<gridA, 256, 0, stream>>>(pk, rpA, (const uint2*)x2bf, nullptr,
                                           (const float4*)embedding, (const uint2*)x1bf,
                                           (const uint2*)x2bf, (float4*)total,
                                           (uint2*)totbf, N_ITEMS);
        // batch user rows
        spmm_batch_pk<<<(BATCH + 3) / 4, 256, 0, stream>>>(pk + NNZ_A, rpU, user,
                                                           (const uint2*)totbf,
                                                           (float4*)out_user, BATCH);
    } else {
        // ---- fallback: round-1 atomic path ----
        const size_t itemBytes = (size_t)N_ITEMS * EMB * sizeof(float);
        float* buf0 = (float*)d_ws;
        float* buf1 = buf0 + (size_t)N_ITEMS * EMB;
        float* user_all = buf1;
        const size_t userBytes = (size_t)N_USERS * EMB * sizeof(float);

        hipMemcpyAsync(total, embedding, itemBytes, hipMemcpyDeviceToDevice, stream);
        const int blkA = (NNZ_A * V4_PER_ROW + 255) / 256;
        const int blkU = (NNZ_U * V4_PER_ROW + 255) / 256;
        const int n4 = N_ITEMS * EMB / 4;
        const int blkAdd = (n4 + 255) / 256;

        hipMemsetAsync(buf0, 0, itemBytes, stream);
        spmm_scatter<<<blkA, 256, 0, stream>>>(adj_vals, adj_rows, adj_cols, embedding, buf0, NNZ_A);
        add_inplace<<<blkAdd, 256, 0, stream>>>(total, buf0, n4);
        hipMemsetAsync(buf1, 0, itemBytes, stream);
        spmm_scatter<<<blkA, 256, 0, stream>>>(adj_vals, adj_rows, adj_cols, buf0, buf1, NNZ_A);
        add_inplace<<<blkAdd, 256, 0, stream>>>(total, buf1, n4);
        hipMemsetAsync(buf0, 0, itemBytes, stream);
        spmm_scatter<<<blkA, 256, 0, stream>>>(adj_vals, adj_rows, adj_cols, buf1, buf0, NNZ_A);
        add_inplace<<<blkAdd, 256, 0, stream>>>(total, buf0, n4);
        hipMemsetAsync(user_all, 0, userBytes, stream);
        spmm_scatter<<<blkU, 256, 0, stream>>>(u_vals, u_rows, u_cols, total, user_all, NNZ_U);
        gather_rows<<<(BATCH * V4_PER_ROW + 255) / 256, 256, 0, stream>>>(user_all, user, out_user, BATCH);
    }
}